// Round 1
// baseline (103.876 us; speedup 1.0000x reference)
//
#include <hip/hip_runtime.h>
#include <hip/hip_bf16.h>

// MaskedChamferDistance: B=64, NV=4096, NL=128, D=256, fp32 in/out.
// pairwise[b,v,l] = a[v] - 2*V.L + b[l]; masked mins both axes; out[b] size 64.
// Strategy: one pass, bf16 MFMA for cross term only, exact fp32 norms.
// Global-max masking is provably a no-op for the results (see analysis).

#define NB 64
#define NVC 4096
#define NLC 128
#define ND 256
#define BM 128
#define LDV 264   // bf16 elems per LDS row (256 + 8 pad -> 2-way bank conflicts only)

using bf16x8 = __attribute__((ext_vector_type(8))) short;
using f32x4  = __attribute__((ext_vector_type(4))) float;

__device__ __forceinline__ unsigned short f2b(float f) {
  unsigned int u = __float_as_uint(f);
  u += 0x7FFFu + ((u >> 16) & 1u);          // round-to-nearest-even
  return (unsigned short)(u >> 16);
}
// monotone float -> uint transform so atomicMin(uint) == float min
__device__ __forceinline__ unsigned int fenc(float f) {
  unsigned int u = __float_as_uint(f);
  return (u & 0x80000000u) ? ~u : (u | 0x80000000u);
}
__device__ __forceinline__ float fdec(unsigned int u) {
  return (u & 0x80000000u) ? __uint_as_float(u & 0x7FFFFFFFu) : __uint_as_float(~u);
}

__global__ __launch_bounds__(512) void chamfer_main(
    const float* __restrict__ vf, const float* __restrict__ lf,
    const float* __restrict__ mask, unsigned int* __restrict__ colmin_g,
    float* __restrict__ rowsum_g)
{
  __shared__ __attribute__((aligned(16))) unsigned short Vlds[BM * LDV];
  __shared__ __attribute__((aligned(16))) unsigned short Llds[NLC * LDV];
  __shared__ float a_lds[BM];        // fp32 |V_row|^2
  __shared__ float bn_lds[NLC];      // fp32 |L_row|^2
  __shared__ float mk_lds[BM];
  __shared__ float rowmin_lds[2][BM];
  __shared__ float colmin_lds[4][NLC];

  const int t  = threadIdx.x;
  const int b  = blockIdx.x >> 5;          // 32 chunks per batch
  const int v0 = (blockIdx.x & 31) * BM;

  // ---- stage V chunk (BM x ND) fp32 -> bf16 LDS, fp32 row norms in-flight ----
  {
    const int row = t >> 2, c4 = t & 3;    // 4 lanes per row, 16 float4 each
    const float* src = vf + ((size_t)b * NVC + v0 + row) * ND;
    float nrm = 0.f;
    #pragma unroll
    for (int i = 0; i < 16; ++i) {
      const int col = (c4 + 4 * i) * 4;
      float4 v = *reinterpret_cast<const float4*>(src + col);
      nrm += v.x * v.x + v.y * v.y + v.z * v.z + v.w * v.w;
      ushort4 h;
      h.x = f2b(v.x); h.y = f2b(v.y); h.z = f2b(v.z); h.w = f2b(v.w);
      *reinterpret_cast<ushort4*>(&Vlds[row * LDV + col]) = h;
    }
    nrm += __shfl_xor(nrm, 1);
    nrm += __shfl_xor(nrm, 2);
    if (c4 == 0) a_lds[row] = nrm;
  }
  // ---- stage L (NLC x ND), same pattern ----
  {
    const int row = t >> 2, c4 = t & 3;
    const float* src = lf + ((size_t)b * NLC + row) * ND;
    float nrm = 0.f;
    #pragma unroll
    for (int i = 0; i < 16; ++i) {
      const int col = (c4 + 4 * i) * 4;
      float4 v = *reinterpret_cast<const float4*>(src + col);
      nrm += v.x * v.x + v.y * v.y + v.z * v.z + v.w * v.w;
      ushort4 h;
      h.x = f2b(v.x); h.y = f2b(v.y); h.z = f2b(v.z); h.w = f2b(v.w);
      *reinterpret_cast<ushort4*>(&Llds[row * LDV + col]) = h;
    }
    nrm += __shfl_xor(nrm, 1);
    nrm += __shfl_xor(nrm, 2);
    if (c4 == 0) bn_lds[row] = nrm;
  }
  if (t < BM) mk_lds[t] = mask[(size_t)b * NVC + v0 + t];
  __syncthreads();

  // ---- MFMA: wave grid 4(m) x 2(n); wave tile 32 rows x 64 cols ----
  const int wid = t >> 6, lane = t & 63;
  const int wm = wid >> 1, wn = wid & 1;
  const int lhi = lane >> 4, llo = lane & 15;

  f32x4 acc[2][4];
  #pragma unroll
  for (int m = 0; m < 2; ++m)
    #pragma unroll
    for (int n = 0; n < 4; ++n)
      acc[m][n] = (f32x4){0.f, 0.f, 0.f, 0.f};

  const int abase0 = (wm * 32 + llo) * LDV;
  const int abase1 = abase0 + 16 * LDV;
  int bbase[4];
  #pragma unroll
  for (int n = 0; n < 4; ++n) bbase[n] = (wn * 64 + n * 16 + llo) * LDV;

  #pragma unroll
  for (int kk = 0; kk < 8; ++kk) {
    const int ko = kk * 32 + lhi * 8;
    bf16x8 af0 = *reinterpret_cast<const bf16x8*>(&Vlds[abase0 + ko]);
    bf16x8 af1 = *reinterpret_cast<const bf16x8*>(&Vlds[abase1 + ko]);
    #pragma unroll
    for (int n = 0; n < 4; ++n) {
      bf16x8 bfr = *reinterpret_cast<const bf16x8*>(&Llds[bbase[n] + ko]);
      acc[0][n] = __builtin_amdgcn_mfma_f32_16x16x32_bf16(af0, bfr, acc[0][n], 0, 0, 0);
      acc[1][n] = __builtin_amdgcn_mfma_f32_16x16x32_bf16(af1, bfr, acc[1][n], 0, 0, 0);
    }
  }

  // ---- epilogue: in-register mins. C/D layout: col=lane&15, row=(lane>>4)*4+reg ----
  float bn[4];
  #pragma unroll
  for (int n = 0; n < 4; ++n) bn[n] = bn_lds[wn * 64 + n * 16 + llo];
  float av[2][4], mk[2][4];
  #pragma unroll
  for (int m = 0; m < 2; ++m)
    #pragma unroll
    for (int r = 0; r < 4; ++r) {
      const int row = wm * 32 + m * 16 + lhi * 4 + r;
      av[m][r] = a_lds[row];
      mk[m][r] = mk_lds[row];
    }

  // row mins: min over l of (b[l] - 2ab); reduce across 16 cols (llo)
  #pragma unroll
  for (int m = 0; m < 2; ++m)
    #pragma unroll
    for (int r = 0; r < 4; ++r) {
      float v = bn[0] - 2.f * acc[m][0][r];
      #pragma unroll
      for (int n = 1; n < 4; ++n) {
        float c = bn[n] - 2.f * acc[m][n][r];
        v = fminf(v, c);
      }
      v = fminf(v, __shfl_xor(v, 1));
      v = fminf(v, __shfl_xor(v, 2));
      v = fminf(v, __shfl_xor(v, 4));
      v = fminf(v, __shfl_xor(v, 8));
      if (llo == 0) rowmin_lds[wn][wm * 32 + m * 16 + lhi * 4 + r] = v;
    }

  // col mins: min over valid v of (a[v] - 2ab); reduce across lhi groups
  #pragma unroll
  for (int n = 0; n < 4; ++n) {
    float v = 3.0e38f;
    #pragma unroll
    for (int m = 0; m < 2; ++m)
      #pragma unroll
      for (int r = 0; r < 4; ++r) {
        float s = av[m][r] - 2.f * acc[m][n][r];
        v = fminf(v, (mk[m][r] != 0.f) ? s : 3.0e38f);
      }
    v = fminf(v, __shfl_xor(v, 16));
    v = fminf(v, __shfl_xor(v, 32));
    if (lhi == 0) colmin_lds[wm][wn * 64 + n * 16 + llo] = v;
  }
  __syncthreads();

  // ---- combine across waves, emit atomics ----
  if (t < BM) {
    // row direction: full min over 128 cols, add a[v], mask, sum -> atomicAdd
    float rm = fminf(rowmin_lds[0][t], rowmin_lds[1][t]);
    float contrib = (mk_lds[t] != 0.f) ? (a_lds[t] + rm) : 0.f;
    #pragma unroll
    for (int off = 32; off >= 1; off >>= 1) contrib += __shfl_xor(contrib, off);
    if ((t & 63) == 0) atomicAdd(rowsum_g + b, contrib);

    // col direction: min over this block's 128 rows, add b[l], global atomicMin
    float cm = fminf(fminf(colmin_lds[0][t], colmin_lds[1][t]),
                     fminf(colmin_lds[2][t], colmin_lds[3][t]));
    atomicMin(colmin_g + (size_t)b * NLC + t, fenc(cm + bn_lds[t]));
  }
}

__global__ __launch_bounds__(256) void chamfer_finalize(
    const float* __restrict__ mask, const unsigned int* __restrict__ colmin_g,
    const float* __restrict__ rowsum_g, float* __restrict__ out)
{
  const int b = blockIdx.x, t = threadIdx.x;
  __shared__ float red[4];

  float nv = 0.f;
  for (int i = t; i < NVC; i += 256) nv += mask[(size_t)b * NVC + i];
  #pragma unroll
  for (int off = 32; off >= 1; off >>= 1) nv += __shfl_xor(nv, off);
  if ((t & 63) == 0) red[t >> 6] = nv;
  __syncthreads();
  const float nvtot = red[0] + red[1] + red[2] + red[3];
  __syncthreads();

  float cs = (t < NLC) ? fdec(colmin_g[(size_t)b * NLC + t]) : 0.f;
  #pragma unroll
  for (int off = 32; off >= 1; off >>= 1) cs += __shfl_xor(cs, off);
  if ((t & 63) == 0) red[t >> 6] = cs;
  __syncthreads();
  if (t == 0) {
    const float cstot = red[0] + red[1] + red[2] + red[3];
    out[b] = cstot / (float)NLC + rowsum_g[b] / nvtot;
  }
}

extern "C" void kernel_launch(void* const* d_in, const int* in_sizes, int n_in,
                              void* d_out, int out_size, void* d_ws, size_t ws_size,
                              hipStream_t stream) {
  const float* vf   = (const float*)d_in[0];
  const float* lf   = (const float*)d_in[1];
  const float* mask = (const float*)d_in[2];
  float* out = (float*)d_out;

  unsigned int* colmin = (unsigned int*)d_ws;
  float* rowsum = (float*)((char*)d_ws + (size_t)NB * NLC * sizeof(unsigned int));

  hipMemsetAsync(colmin, 0xFF, (size_t)NB * NLC * sizeof(unsigned int), stream);
  hipMemsetAsync(rowsum, 0, (size_t)NB * sizeof(float), stream);

  chamfer_main<<<dim3(NB * (NVC / BM)), dim3(512), 0, stream>>>(vf, lf, mask, colmin, rowsum);
  chamfer_finalize<<<dim3(NB), dim3(256), 0, stream>>>(mask, colmin, rowsum, out);
}